// Round 1
// baseline (297.306 us; speedup 1.0000x reference)
//
#include <hip/hip_runtime.h>

#define TOPK 500
#define NCLS 80
#define NPOS 196   // 14*14
#define NLEV 5
#define OUT_B_OFF 0
#define OUT_C_OFF 2000
#define OUT_R_OFF 42000

// ---------------- workspace layout (bytes) ----------------
// 0      : int state[16]  0:k 1:cntGt 2:prefix 3:threshold 4:cntEq 5:nGt 6:nEq
// 64     : int hist[4][256]
// 8192   : int gtIdx[512]
// 12288  : int eqIdx[4096]
// 32768  : int topIdx[512]
// 40960  : float scores[N]

__global__ void k_init(int* state, int* hist) {
    int t = threadIdx.x;
    if (t < 1024) hist[t] = 0;
    if (t == 0) {
        state[0] = TOPK; state[1] = 0; state[2] = 0; state[3] = 0;
        state[4] = 0; state[5] = 0; state[6] = 0;
    }
}

__global__ void k_scores(const float* __restrict__ cls, float* __restrict__ scores, int N) {
    int i = blockIdx.x * blockDim.x + threadIdx.x;
    if (i >= N) return;
    const float4* p = (const float4*)(cls + (size_t)i * NCLS);
    float m = -1e30f;
#pragma unroll
    for (int k = 0; k < NCLS / 4; ++k) {
        float4 v = p[k];
        m = fmaxf(m, fmaxf(fmaxf(v.x, v.y), fmaxf(v.z, v.w)));
    }
    scores[i] = m;
}

__global__ void k_hist(const float* __restrict__ scores, int N,
                       const int* __restrict__ state, int* __restrict__ hist, int pass) {
    __shared__ int lh[256];
    lh[threadIdx.x] = 0;
    __syncthreads();
    unsigned prefix = (unsigned)state[2];
    int shift = 24 - 8 * pass;
    unsigned mask = (pass == 0) ? 0u : (0xFFFFFFFFu << (32 - 8 * pass));
    for (int i = blockIdx.x * blockDim.x + threadIdx.x; i < N; i += gridDim.x * blockDim.x) {
        unsigned bits = __float_as_uint(scores[i]);
        if ((bits & mask) == prefix)
            atomicAdd(&lh[(bits >> shift) & 0xFF], 1);
    }
    __syncthreads();
    int c = lh[threadIdx.x];
    if (c) atomicAdd(&hist[pass * 256 + threadIdx.x], c);
}

__global__ void k_pick(int* state, const int* hist, int pass) {
    if (threadIdx.x != 0) return;
    int k = state[0];
    int cntGt = state[1];
    unsigned prefix = (unsigned)state[2];
    const int* h = hist + pass * 256;
    int cum = 0, chosen = 0;
    for (int b = 255; b >= 0; --b) {
        if (cum + h[b] >= k) { chosen = b; break; }
        cum += h[b];
    }
    int shift = 24 - 8 * pass;
    cntGt += cum;
    k -= cum;
    prefix |= ((unsigned)chosen) << shift;
    state[0] = k; state[1] = cntGt; state[2] = (int)prefix;
    if (pass == 3) { state[3] = (int)prefix; state[4] = h[chosen]; }
}

__global__ void k_collect(const float* __restrict__ scores, int N,
                          int* state, int* gtIdx, int* eqIdx) {
    int i = blockIdx.x * blockDim.x + threadIdx.x;
    if (i >= N) return;
    unsigned T = (unsigned)state[3];
    unsigned bits = __float_as_uint(scores[i]);
    if (bits > T) {
        int p = atomicAdd(&state[5], 1);
        if (p < 512) gtIdx[p] = i;
    } else if (bits == T) {
        int p = atomicAdd(&state[6], 1);
        if (p < 4096) eqIdx[p] = i;
    }
}

// 1024-wide bitonic sort, key = (score_bits<<32) | ~idx  -> (score desc, idx asc)
__global__ void k_sort(const float* __restrict__ scores, const int* __restrict__ state,
                       const int* __restrict__ gtIdx, const int* __restrict__ eqIdx,
                       int* __restrict__ topIdx) {
    __shared__ unsigned long long key[1024];
    int tid = threadIdx.x;
    int cntGt = min(state[5], 512);
    int nEq   = min(state[6], 4096);
    int eqTake = min(nEq, 1024 - cntGt);
    int total = cntGt + eqTake;
    unsigned long long kk = 0ull;
    if (tid < cntGt) {
        int idx = gtIdx[tid];
        kk = ((unsigned long long)__float_as_uint(scores[idx]) << 32) | (unsigned)(~idx);
    } else if (tid < total) {
        int idx = eqIdx[tid - cntGt];
        kk = ((unsigned long long)(unsigned)state[3] << 32) | (unsigned)(~idx);
    }
    key[tid] = kk;
    __syncthreads();
    for (int k = 2; k <= 1024; k <<= 1) {
        for (int j = k >> 1; j > 0; j >>= 1) {
            int ixj = tid ^ j;
            if (ixj > tid) {
                unsigned long long a = key[tid], b = key[ixj];
                bool desc = ((tid & k) == 0);
                if (desc ? (a < b) : (a > b)) { key[tid] = b; key[ixj] = a; }
            }
            __syncthreads();
        }
    }
    if (tid < TOPK) topIdx[tid] = (int)(~(unsigned)(key[tid] & 0xFFFFFFFFull));
}

__global__ void k_gather(const float* __restrict__ boxes, const float* __restrict__ cls,
                         const int* __restrict__ topIdx, float* __restrict__ out) {
    int j = blockIdx.x;
    int t = threadIdx.x;
    int idx = topIdx[j];
    if (t < NCLS)            out[OUT_C_OFF + j * NCLS + t] = cls[(size_t)idx * NCLS + t];
    else if (t < NCLS + 4)   out[OUT_B_OFF + j * 4 + (t - NCLS)] = boxes[(size_t)idx * 4 + (t - NCLS)];
}

__global__ __launch_bounds__(256) void k_roi(
    const float* __restrict__ boxes, const int* __restrict__ topIdx,
    const int* __restrict__ ishape,
    const float* __restrict__ p3, const float* __restrict__ p4,
    const float* __restrict__ p5, const float* __restrict__ p6,
    const float* __restrict__ p7,
    float* __restrict__ out) {
    int bid = blockIdx.x;
    int j   = bid / NPOS;
    int pos = bid - j * NPOS;
    int y = pos / 14, x = pos - (pos / 14) * 14;
    int idx = topIdx[j];
    float bx1 = boxes[idx * 4 + 0];
    float by1 = boxes[idx * 4 + 1];
    float bx2 = boxes[idx * 4 + 2];
    float by2 = boxes[idx * 4 + 3];
    float hf = (float)ishape[1];
    float wf = (float)ishape[2];
    float ny1 = by1 / hf, nx1 = bx1 / wf, ny2 = by2 / hf, nx2 = bx2 / wf;
    float ty = (float)y / 13.0f;
    float tx = (float)x / 13.0f;
    const float* fm[5] = {p3, p4, p5, p6, p7};
    int c = threadIdx.x;
    float* o = out + OUT_R_OFF + (size_t)bid * (NLEV * 256) + c;
#pragma unroll
    for (int l = 0; l < NLEV; ++l) {
        int H = 128 >> l;
        float Hm1 = (float)(H - 1);
        float ys = (ny1 + ty * (ny2 - ny1)) * Hm1;
        float xs = (nx1 + tx * (nx2 - nx1)) * Hm1;
        float y0f = floorf(ys), x0f = floorf(xs);
        float wy = ys - y0f, wx = xs - x0f;
        int y0  = min(max((int)y0f, 0), H - 1);
        int y1c = min(max((int)y0f + 1, 0), H - 1);
        int x0  = min(max((int)x0f, 0), H - 1);
        int x1c = min(max((int)x0f + 1, 0), H - 1);
        bool valid = (ys >= 0.0f) && (ys <= Hm1) && (xs >= 0.0f) && (xs <= Hm1);
        const float* f = fm[l];
        float v00 = f[((size_t)(y0 * H + x0) << 8) + c];
        float v01 = f[((size_t)(y0 * H + x1c) << 8) + c];
        float v10 = f[((size_t)(y1c * H + x0) << 8) + c];
        float v11 = f[((size_t)(y1c * H + x1c) << 8) + c];
        float r = (1.0f - wy) * (1.0f - wx) * v00 + (1.0f - wy) * wx * v01
                + wy * (1.0f - wx) * v10 + wy * wx * v11;
        o[l * 256] = valid ? r : 0.0f;
    }
}

extern "C" void kernel_launch(void* const* d_in, const int* in_sizes, int n_in,
                              void* d_out, int out_size, void* d_ws, size_t ws_size,
                              hipStream_t stream) {
    const int*   ishape = (const int*)d_in[0];
    const float* boxes  = (const float*)d_in[1];
    const float* cls    = (const float*)d_in[2];
    const float* p3     = (const float*)d_in[3];
    const float* p4     = (const float*)d_in[4];
    const float* p5     = (const float*)d_in[5];
    const float* p6     = (const float*)d_in[6];
    const float* p7     = (const float*)d_in[7];
    float* out = (float*)d_out;

    int N = in_sizes[2] / NCLS;   // 196416

    char* ws = (char*)d_ws;
    int*   state  = (int*)(ws + 0);
    int*   hist   = (int*)(ws + 64);
    int*   gtIdx  = (int*)(ws + 8192);
    int*   eqIdx  = (int*)(ws + 12288);
    int*   topIdx = (int*)(ws + 32768);
    float* scores = (float*)(ws + 40960);

    hipLaunchKernelGGL(k_init, dim3(1), dim3(1024), 0, stream, state, hist);
    hipLaunchKernelGGL(k_scores, dim3((N + 255) / 256), dim3(256), 0, stream, cls, scores, N);
    for (int pass = 0; pass < 4; ++pass) {
        hipLaunchKernelGGL(k_hist, dim3(128), dim3(256), 0, stream, scores, N, state, hist, pass);
        hipLaunchKernelGGL(k_pick, dim3(1), dim3(64), 0, stream, state, hist, pass);
    }
    hipLaunchKernelGGL(k_collect, dim3((N + 255) / 256), dim3(256), 0, stream, scores, N, state, gtIdx, eqIdx);
    hipLaunchKernelGGL(k_sort, dim3(1), dim3(1024), 0, stream, scores, state, gtIdx, eqIdx, topIdx);
    hipLaunchKernelGGL(k_gather, dim3(TOPK), dim3(128), 0, stream, boxes, cls, topIdx, out);
    hipLaunchKernelGGL(k_roi, dim3(TOPK * NPOS), dim3(256), 0, stream,
                       boxes, topIdx, ishape, p3, p4, p5, p6, p7, out);
}

// Round 3
// 250.664 us; speedup vs baseline: 1.1861x; 1.1861x over previous
//
#include <hip/hip_runtime.h>

#define TOPK 500
#define NCLS 80
#define NPOS 196   // 14*14
#define NLEV 5
#define OUT_B_OFF 0
#define OUT_C_OFF 2000
#define OUT_R_OFF 42000

typedef float  nfloat4 __attribute__((ext_vector_type(4)));

// ---------------- workspace layout (bytes) ----------------
#define WS_STATE   0
#define WS_HIST    64
#define WS_GT      8192
#define WS_EQ      12288
#define WS_TOP     32768
#define WS_SCORES  40960
#define WS_BF16    (1u << 20)
#define FEAT_PX    21824          // 16384+4096+1024+256+64
#define BF16_BYTES ((size_t)FEAT_PX * 256 * 2)

__global__ void k_init(int* state, int* hist) {
    int t = threadIdx.x;
    if (t < 1024) hist[t] = 0;
    if (t < 16) state[t] = 0;
}

__device__ inline unsigned short f2bf(float f) {
    unsigned u = __float_as_uint(f);
    return (unsigned short)((u + 0x7FFFu + ((u >> 16) & 1u)) >> 16);
}

// convert all 5 feature maps (f32) -> contiguous bf16 buffer, float4 at a time
__global__ __launch_bounds__(256) void k_cvt(
    const float* __restrict__ p3, const float* __restrict__ p4,
    const float* __restrict__ p5, const float* __restrict__ p6,
    const float* __restrict__ p7, ushort* __restrict__ dst) {
    int i = blockIdx.x * 256 + threadIdx.x;   // float4 index, total 1,396,736
    const int n0 = 1048576, n1 = 262144, n2 = 65536, n3 = 16384;
    const float* src; int off;
    if (i < n0)                { src = p3; off = i; }
    else if (i < n0+n1)        { src = p4; off = i - n0; }
    else if (i < n0+n1+n2)     { src = p5; off = i - n0 - n1; }
    else if (i < n0+n1+n2+n3)  { src = p6; off = i - n0 - n1 - n2; }
    else                       { src = p7; off = i - n0 - n1 - n2 - n3; }
    float4 v = ((const float4*)src)[off];
    ushort4 r;
    r.x = f2bf(v.x); r.y = f2bf(v.y); r.z = f2bf(v.z); r.w = f2bf(v.w);
    ((ushort4*)dst)[i] = r;
}

// scores + pass-0 histogram (top byte)
__global__ __launch_bounds__(256) void k_scores(
    const float* __restrict__ cls, float* __restrict__ scores,
    int* __restrict__ hist, int N) {
    __shared__ int lh[256];
    int t = threadIdx.x;
    lh[t] = 0;
    __syncthreads();
    int i = blockIdx.x * 256 + t;
    if (i < N) {
        const float4* p = (const float4*)(cls + (size_t)i * NCLS);
        float m = -1e30f;
#pragma unroll
        for (int k = 0; k < NCLS / 4; ++k) {
            float4 v = p[k];
            m = fmaxf(m, fmaxf(fmaxf(v.x, v.y), fmaxf(v.z, v.w)));
        }
        scores[i] = m;
        atomicAdd(&lh[__float_as_uint(m) >> 24], 1);
    }
    __syncthreads();
    int c = lh[t];
    if (c) atomicAdd(&hist[t], c);
}

// replay radix picks from completed histograms (scores are positive floats)
__device__ inline unsigned replay_prefix(const int* hist, int passes) {
    int k = TOPK;
    unsigned prefix = 0;
    for (int p = 0; p < passes; ++p) {
        const int* h = hist + (p << 8);
        int cum = 0, chosen = 0;
        for (int b = 255; b >= 0; --b) {
            int hb = h[b];
            if (cum + hb >= k) { chosen = b; break; }
            cum += hb;
        }
        k -= cum;
        prefix |= ((unsigned)chosen) << (24 - 8 * p);
    }
    return prefix;
}

__global__ __launch_bounds__(256) void k_hist(
    const float* __restrict__ scores, int N,
    int* __restrict__ hist, int pass) {
    __shared__ int lh[256];
    __shared__ unsigned s_prefix;
    int t = threadIdx.x;
    lh[t] = 0;
    if (t == 0) s_prefix = replay_prefix(hist, pass);
    __syncthreads();
    unsigned prefix = s_prefix;
    int shift = 24 - 8 * pass;
    unsigned mask = 0xFFFFFFFFu << (32 - 8 * pass);
    for (int i = blockIdx.x * blockDim.x + t; i < N; i += gridDim.x * blockDim.x) {
        unsigned bits = __float_as_uint(scores[i]);
        if ((bits & mask) == prefix)
            atomicAdd(&lh[(bits >> shift) & 0xFF], 1);
    }
    __syncthreads();
    int c = lh[t];
    if (c) atomicAdd(&hist[pass * 256 + t], c);
}

__global__ __launch_bounds__(256) void k_collect(
    const float* __restrict__ scores, int N, const int* __restrict__ hist,
    int* state, int* gtIdx, int* eqIdx) {
    __shared__ unsigned sT;
    if (threadIdx.x == 0) sT = replay_prefix(hist, 4);
    __syncthreads();
    unsigned T = sT;
    int i = blockIdx.x * blockDim.x + threadIdx.x;
    if (i >= N) return;
    unsigned bits = __float_as_uint(scores[i]);
    if (bits > T) {
        int p = atomicAdd(&state[5], 1);
        if (p < 512) gtIdx[p] = i;
    } else if (bits == T) {
        int p = atomicAdd(&state[6], 1);
        if (p < 4096) eqIdx[p] = i;
    }
}

// 1024-wide bitonic sort, key = (score_bits<<32) | ~idx -> (score desc, idx asc)
__global__ void k_sort(const float* __restrict__ scores, const int* __restrict__ hist,
                       const int* __restrict__ state,
                       const int* __restrict__ gtIdx, const int* __restrict__ eqIdx,
                       int* __restrict__ topIdx) {
    __shared__ unsigned long long key[1024];
    __shared__ unsigned sT;
    int tid = threadIdx.x;
    if (tid == 0) sT = replay_prefix(hist, 4);
    __syncthreads();
    unsigned T = sT;
    int cntGt = min(state[5], 512);
    int nEq   = min(state[6], 4096);
    int eqTake = min(nEq, 1024 - cntGt);
    int total = cntGt + eqTake;
    unsigned long long kk = 0ull;
    if (tid < cntGt) {
        int idx = gtIdx[tid];
        kk = ((unsigned long long)__float_as_uint(scores[idx]) << 32) | (unsigned)(~idx);
    } else if (tid < total) {
        int idx = eqIdx[tid - cntGt];
        kk = ((unsigned long long)T << 32) | (unsigned)(~idx);
    }
    key[tid] = kk;
    __syncthreads();
    for (int k = 2; k <= 1024; k <<= 1) {
        for (int j = k >> 1; j > 0; j >>= 1) {
            int ixj = tid ^ j;
            if (ixj > tid) {
                unsigned long long a = key[tid], b = key[ixj];
                bool desc = ((tid & k) == 0);
                if (desc ? (a < b) : (a > b)) { key[tid] = b; key[ixj] = a; }
            }
            __syncthreads();
        }
    }
    if (tid < TOPK) topIdx[tid] = (int)(~(unsigned)(key[tid] & 0xFFFFFFFFull));
}

__global__ void k_gather(const float* __restrict__ boxes, const float* __restrict__ cls,
                         const int* __restrict__ topIdx, float* __restrict__ out) {
    int j = blockIdx.x;
    int t = threadIdx.x;
    int idx = topIdx[j];
    if (t < NCLS)            out[OUT_C_OFF + j * NCLS + t] = cls[(size_t)idx * NCLS + t];
    else if (t < NCLS + 4)   out[OUT_B_OFF + j * 4 + (t - NCLS)] = boxes[(size_t)idx * 4 + (t - NCLS)];
}

// ROI: 4 positions per 256-thread block; 64 lanes/position, 4 channels/lane.
// USE_BF16=1 reads the converted ws buffer (ushort4/8B per corner).
template <int USE_BF16>
__global__ __launch_bounds__(256) void k_roi(
    const float* __restrict__ boxes, const int* __restrict__ topIdx,
    const int* __restrict__ ishape, const ushort* __restrict__ feat,
    const float* __restrict__ f0, const float* __restrict__ f1,
    const float* __restrict__ f2, const float* __restrict__ f3,
    const float* __restrict__ f4,
    float* __restrict__ out) {
    const int lvlOff[5] = {0, 16384, 20480, 21504, 21760};
    int P  = blockIdx.x * 4 + (threadIdx.x >> 6);   // global position, < 98000
    int c4 = threadIdx.x & 63;                      // channel group (4 ch)
    int j = P / NPOS;
    int pos = P - j * NPOS;
    int y = pos / 14, x = pos - (pos / 14) * 14;
    int idx = topIdx[j];
    float bx1 = boxes[idx * 4 + 0];
    float by1 = boxes[idx * 4 + 1];
    float bx2 = boxes[idx * 4 + 2];
    float by2 = boxes[idx * 4 + 3];
    float hf = (float)ishape[1];
    float wf = (float)ishape[2];
    float ny1 = by1 / hf, nx1 = bx1 / wf, ny2 = by2 / hf, nx2 = bx2 / wf;
    float ty = (float)y / 13.0f;
    float tx = (float)x / 13.0f;
    const float* fm[5] = {f0, f1, f2, f3, f4};
    float* o = out + OUT_R_OFF + (size_t)P * (NLEV * 256);
#pragma unroll
    for (int l = 0; l < NLEV; ++l) {
        int H = 128 >> l;
        float Hm1 = (float)(H - 1);
        float ys = (ny1 + ty * (ny2 - ny1)) * Hm1;
        float xs = (nx1 + tx * (nx2 - nx1)) * Hm1;
        float y0f = floorf(ys), x0f = floorf(xs);
        float wy = ys - y0f, wx = xs - x0f;
        int y0  = min(max((int)y0f, 0), H - 1);
        int y1c = min(max((int)y0f + 1, 0), H - 1);
        int x0  = min(max((int)x0f, 0), H - 1);
        int x1c = min(max((int)x0f + 1, 0), H - 1);
        bool valid = (ys >= 0.0f) && (ys <= Hm1) && (xs >= 0.0f) && (xs <= Hm1);
        float w00 = (1.0f - wy) * (1.0f - wx);
        float w01 = (1.0f - wy) * wx;
        float w10 = wy * (1.0f - wx);
        float w11 = wy * wx;
        nfloat4 res;
        if (USE_BF16) {
            const ushort* base = feat + ((size_t)lvlOff[l] << 8);
            ushort4 a = ((const ushort4*)(base + ((size_t)(y0  * H + x0 ) << 8)))[c4];
            ushort4 b = ((const ushort4*)(base + ((size_t)(y0  * H + x1c) << 8)))[c4];
            ushort4 c = ((const ushort4*)(base + ((size_t)(y1c * H + x0 ) << 8)))[c4];
            ushort4 d = ((const ushort4*)(base + ((size_t)(y1c * H + x1c) << 8)))[c4];
#define BF(u) __uint_as_float(((unsigned)(u)) << 16)
            res.x = w00 * BF(a.x) + w01 * BF(b.x) + w10 * BF(c.x) + w11 * BF(d.x);
            res.y = w00 * BF(a.y) + w01 * BF(b.y) + w10 * BF(c.y) + w11 * BF(d.y);
            res.z = w00 * BF(a.z) + w01 * BF(b.z) + w10 * BF(c.z) + w11 * BF(d.z);
            res.w = w00 * BF(a.w) + w01 * BF(b.w) + w10 * BF(c.w) + w11 * BF(d.w);
#undef BF
        } else {
            const float* f = fm[l];
            float4 a = ((const float4*)(f + ((size_t)(y0  * H + x0 ) << 8)))[c4];
            float4 b = ((const float4*)(f + ((size_t)(y0  * H + x1c) << 8)))[c4];
            float4 c = ((const float4*)(f + ((size_t)(y1c * H + x0 ) << 8)))[c4];
            float4 d = ((const float4*)(f + ((size_t)(y1c * H + x1c) << 8)))[c4];
            res.x = w00 * a.x + w01 * b.x + w10 * c.x + w11 * d.x;
            res.y = w00 * a.y + w01 * b.y + w10 * c.y + w11 * d.y;
            res.z = w00 * a.z + w01 * b.z + w10 * c.z + w11 * d.z;
            res.w = w00 * a.w + w01 * b.w + w10 * c.w + w11 * d.w;
        }
        if (!valid) { res.x = 0.f; res.y = 0.f; res.z = 0.f; res.w = 0.f; }
        __builtin_nontemporal_store(res, (nfloat4*)(o + l * 256) + c4);
    }
}

extern "C" void kernel_launch(void* const* d_in, const int* in_sizes, int n_in,
                              void* d_out, int out_size, void* d_ws, size_t ws_size,
                              hipStream_t stream) {
    const int*   ishape = (const int*)d_in[0];
    const float* boxes  = (const float*)d_in[1];
    const float* cls    = (const float*)d_in[2];
    const float* p3     = (const float*)d_in[3];
    const float* p4     = (const float*)d_in[4];
    const float* p5     = (const float*)d_in[5];
    const float* p6     = (const float*)d_in[6];
    const float* p7     = (const float*)d_in[7];
    float* out = (float*)d_out;

    int N = in_sizes[2] / NCLS;   // 196416

    char* ws = (char*)d_ws;
    int*    state  = (int*)(ws + WS_STATE);
    int*    hist   = (int*)(ws + WS_HIST);
    int*    gtIdx  = (int*)(ws + WS_GT);
    int*    eqIdx  = (int*)(ws + WS_EQ);
    int*    topIdx = (int*)(ws + WS_TOP);
    float*  scores = (float*)(ws + WS_SCORES);
    ushort* feat   = (ushort*)(ws + WS_BF16);

    bool useBf16 = ws_size >= (size_t)WS_BF16 + BF16_BYTES;

    hipLaunchKernelGGL(k_init, dim3(1), dim3(1024), 0, stream, state, hist);
    if (useBf16)
        hipLaunchKernelGGL(k_cvt, dim3(5456), dim3(256), 0, stream, p3, p4, p5, p6, p7, feat);
    hipLaunchKernelGGL(k_scores, dim3((N + 255) / 256), dim3(256), 0, stream, cls, scores, hist, N);
    for (int pass = 1; pass < 4; ++pass)
        hipLaunchKernelGGL(k_hist, dim3(256), dim3(256), 0, stream, scores, N, hist, pass);
    hipLaunchKernelGGL(k_collect, dim3((N + 255) / 256), dim3(256), 0, stream,
                       scores, N, hist, state, gtIdx, eqIdx);
    hipLaunchKernelGGL(k_sort, dim3(1), dim3(1024), 0, stream,
                       scores, hist, state, gtIdx, eqIdx, topIdx);
    hipLaunchKernelGGL(k_gather, dim3(TOPK), dim3(128), 0, stream, boxes, cls, topIdx, out);
    if (useBf16)
        hipLaunchKernelGGL((k_roi<1>), dim3(TOPK * NPOS / 4), dim3(256), 0, stream,
                           boxes, topIdx, ishape, feat, p3, p4, p5, p6, p7, out);
    else
        hipLaunchKernelGGL((k_roi<0>), dim3(TOPK * NPOS / 4), dim3(256), 0, stream,
                           boxes, topIdx, ishape, feat, p3, p4, p5, p6, p7, out);
}